// Round 11
// baseline (26258.575 us; speedup 1.0000x reference)
//
#include <hip/hip_runtime.h>
#include <math.h>

constexpr int B    = 512;
constexpr int T    = 64;
constexpr int H    = 512;
constexpr int V    = 780;
constexpr int N_AT = 40;
constexpr int KC   = 4;
constexpr int NB   = 8;
constexpr int BT   = B * T;      // 32768
constexpr int NMSG = BT + 1;     // 32769
constexpr int BH   = B * H;      // 262144
constexpr int NBLK = 256;        // persistent grid (1 block/CU, guaranteed resident)

__device__ __forceinline__ float sigf(float x) { return 1.f / (1.f + expf(-x)); }

// ===========================================================================
// Hierarchical device-wide barrier.
//  - arrive: ONE release fence; relaxed RMW on per-group line (<=32 contenders)
//  - group-last: relaxed RMW on global line (8 contenders); global-last stores go
//  - exit: read-only relaxed polls of go; ONE acquire fence
// bar layout (unsigned): [g*16] local counters g=0..7, [128] global, [144] go
// ===========================================================================
__device__ __forceinline__ void gbar2(unsigned* bar, unsigned& epoch, int bid)
{
    __syncthreads();
    if (threadIdx.x == 0) {
        epoch += 1;
        __builtin_amdgcn_fence(__ATOMIC_RELEASE, "agent");
        const int g = bid >> 5;
        const unsigned a = __hip_atomic_fetch_add(&bar[g * 16], 1u,
                              __ATOMIC_RELAXED, __HIP_MEMORY_SCOPE_AGENT);
        if ((a & 31u) == 31u) {
            const unsigned ga = __hip_atomic_fetch_add(&bar[128], 1u,
                                   __ATOMIC_RELAXED, __HIP_MEMORY_SCOPE_AGENT);
            if ((ga & 7u) == 7u)
                __hip_atomic_store(&bar[144], epoch,
                                   __ATOMIC_RELAXED, __HIP_MEMORY_SCOPE_AGENT);
        }
        while (__hip_atomic_load(&bar[144], __ATOMIC_RELAXED,
                                 __HIP_MEMORY_SCOPE_AGENT) < epoch)
            __builtin_amdgcn_s_sleep(2);
        __builtin_amdgcn_fence(__ATOMIC_ACQUIRE, "agent");
    }
    __syncthreads();
}

// ===========================================================================
// Phase bodies
// ===========================================================================

// z/h dual GEMM (verified r8/r10): 128 blocks of 32x64 tiles, K=1024.
// table[b*T+t+1] = (1-z)*sumh + z*tanh(preh)
__device__ __forceinline__ void ph_zh(int t, int bx, int tid,
    float* As1, float* As2, float* W1s, float* W2s,
    const float* __restrict__ xb, const float* __restrict__ sumh,
    const float* __restrict__ sumg,
    const float* __restrict__ Wz, const float* __restrict__ bz,
    const float* __restrict__ Wh, const float* __restrict__ bh,
    float* __restrict__ table)
{
    const int rt = bx >> 3, ct = bx & 7, row0 = rt * 32, col0 = ct * 64;
    const int tm = tid >> 4, tn = tid & 15;
    const int ak = tid & 31, am0 = tid >> 5, wn = tid & 63, wk0 = tid >> 6;
    float az[2][4] = {}, ah[2][4] = {};

    for (int k0 = 0; k0 < H; k0 += 32) {
#pragma unroll
        for (int it = 0; it < 4; ++it) {
            const int m = am0 + it * 8;
            As1[ak * 38 + m] = xb[(size_t)(row0 + m) * H + k0 + ak];
        }
#pragma unroll
        for (int it = 0; it < 8; ++it) {
            const int kk = wk0 + it * 4;
            W1s[kk * 68 + wn] = Wz[(size_t)(k0 + kk) * H + col0 + wn];
            W2s[kk * 68 + wn] = Wh[(size_t)(k0 + kk) * H + col0 + wn];
        }
        __syncthreads();
#pragma unroll
        for (int kk = 0; kk < 32; ++kk) {
            const float a0 = As1[kk * 38 + tm * 2];
            const float a1 = As1[kk * 38 + tm * 2 + 1];
            float w1[4], w2[4];
            *(float4*)w1 = *(const float4*)&W1s[kk * 68 + tn * 4];
            *(float4*)w2 = *(const float4*)&W2s[kk * 68 + tn * 4];
#pragma unroll
            for (int j = 0; j < 4; ++j) {
                az[0][j] = fmaf(a0, w1[j], az[0][j]);
                az[1][j] = fmaf(a1, w1[j], az[1][j]);
                ah[0][j] = fmaf(a0, w2[j], ah[0][j]);
                ah[1][j] = fmaf(a1, w2[j], ah[1][j]);
            }
        }
        __syncthreads();
    }
    for (int k0 = 0; k0 < H; k0 += 32) {
#pragma unroll
        for (int it = 0; it < 4; ++it) {
            const int m = am0 + it * 8;
            As1[ak * 38 + m] = sumh[(size_t)(row0 + m) * H + k0 + ak];
            As2[ak * 38 + m] = sumg[(size_t)(row0 + m) * H + k0 + ak];
        }
#pragma unroll
        for (int it = 0; it < 8; ++it) {
            const int kk = wk0 + it * 4;
            W1s[kk * 68 + wn] = Wz[(size_t)(H + k0 + kk) * H + col0 + wn];
            W2s[kk * 68 + wn] = Wh[(size_t)(H + k0 + kk) * H + col0 + wn];
        }
        __syncthreads();
#pragma unroll
        for (int kk = 0; kk < 32; ++kk) {
            const float a10 = As1[kk * 38 + tm * 2];
            const float a11 = As1[kk * 38 + tm * 2 + 1];
            const float a20 = As2[kk * 38 + tm * 2];
            const float a21 = As2[kk * 38 + tm * 2 + 1];
            float w1[4], w2[4];
            *(float4*)w1 = *(const float4*)&W1s[kk * 68 + tn * 4];
            *(float4*)w2 = *(const float4*)&W2s[kk * 68 + tn * 4];
#pragma unroll
            for (int j = 0; j < 4; ++j) {
                az[0][j] = fmaf(a10, w1[j], az[0][j]);
                az[1][j] = fmaf(a11, w1[j], az[1][j]);
                ah[0][j] = fmaf(a20, w2[j], ah[0][j]);
                ah[1][j] = fmaf(a21, w2[j], ah[1][j]);
            }
        }
        __syncthreads();
    }
#pragma unroll
    for (int i = 0; i < 2; ++i) {
        const int b = row0 + tm * 2 + i;
        const float4 s4 = *(const float4*)&sumh[(size_t)b * H + col0 + tn * 4];
        const float sv[4] = {s4.x, s4.y, s4.z, s4.w};
        float out[4];
#pragma unroll
        for (int j = 0; j < 4; ++j) {
            const int c = col0 + tn * 4 + j;
            const float z  = sigf(az[i][j] + bz[c]);
            const float ph = tanhf(ah[i][j] + bh[c]);
            out[j] = (1.f - z) * sv[j] + z * ph;
        }
        *(float4*)&table[((size_t)b * T + t + 1) * H + col0 + tn * 4] = *(float4*)out;
    }
}

// clique gather (verified): xb[b][h4..] for step tg
__device__ __forceinline__ void ph_xgather(int tg, int unit,
    const float* __restrict__ node_rep, const int* __restrict__ cliq,
    float* __restrict__ xb)
{
    const int b = unit >> 7, h4 = (unit & 127) * 4;
    const int* ci = cliq + ((size_t)b * T + tg) * KC;
    float4 s = {0.f, 0.f, 0.f, 0.f};
#pragma unroll
    for (int j = 0; j < KC; ++j) {
        const float4 v = *(const float4*)&node_rep[((size_t)b * N_AT + ci[j]) * H + h4];
        s.x += v.x; s.y += v.y; s.z += v.z; s.w += v.w;
    }
    *(float4*)&xb[(size_t)b * H + h4] = s;
}

// Fused hU-GEMM + masked sums for step tg. One 32x64 tile of the M=4096
// hU matrix (rows = b*NB+n, masked-gathered from table), epilogue reduces
// over n with sigmoid gating -> sumh/sumg for 4 b's x 64 cols.
__device__ __forceinline__ void ph_sums2(int tg, int job, int tid,
    float* As, float* Ws_, float* sredH, float* sredG,
    const int* __restrict__ nh, const float* __restrict__ xr_all,
    const float* __restrict__ table, const float* __restrict__ Ur,
    float* __restrict__ sumh, float* __restrict__ sumg)
{
    const int rt = job >> 3, ct = job & 7, row0 = rt * 32, col0 = ct * 64;
    const int tm = tid >> 4, tn = tid & 15;
    const int ak = tid & 31, am0 = tid >> 5, wn = tid & 63, wk0 = tid >> 6;
    float ac[2][4] = {};

    for (int k0 = 0; k0 < H; k0 += 32) {
#pragma unroll
        for (int it = 0; it < 4; ++it) {
            const int m = am0 + it * 8, gm = row0 + m;
            const int b = gm >> 3, n = gm & 7;
            const int gi = nh[((size_t)b * T + tg) * NB + n];
            const bool msk = (gi != 0 && ((gi - 1) & 63) == tg);
            As[ak * 38 + m] = msk ? 0.f : table[(size_t)gi * H + k0 + ak];
        }
#pragma unroll
        for (int it = 0; it < 8; ++it) {
            const int kk = wk0 + it * 4;
            Ws_[kk * 68 + wn] = Ur[(size_t)(k0 + kk) * H + col0 + wn];
        }
        __syncthreads();
#pragma unroll
        for (int kk = 0; kk < 32; ++kk) {
            const float a0 = As[kk * 38 + tm * 2];
            const float a1 = As[kk * 38 + tm * 2 + 1];
            float w[4];
            *(float4*)w = *(const float4*)&Ws_[kk * 68 + tn * 4];
#pragma unroll
            for (int j = 0; j < 4; ++j) {
                ac[0][j] = fmaf(a0, w[j], ac[0][j]);
                ac[1][j] = fmaf(a1, w[j], ac[1][j]);
            }
        }
        __syncthreads();
    }
    // epilogue: ac = hU rows (U_r has no bias). Gated contributions to LDS.
#pragma unroll
    for (int i = 0; i < 2; ++i) {
        const int gm = row0 + tm * 2 + i;
        const int b = gm >> 3, n = gm & 7;
        const int gi = nh[((size_t)b * T + tg) * NB + n];
        const bool msk = (gi != 0 && ((gi - 1) & 63) == tg);
        float4 tv = {0.f, 0.f, 0.f, 0.f};
        if (!msk) tv = *(const float4*)&table[(size_t)gi * H + col0 + tn * 4];
        const float4 x4 = *(const float4*)&xr_all[((size_t)b * T + tg) * H + col0 + tn * 4];
        const float tvv[4] = {tv.x, tv.y, tv.z, tv.w};
        const float xrv[4] = {x4.x, x4.y, x4.z, x4.w};
#pragma unroll
        for (int j = 0; j < 4; ++j) {
            const float r = sigf(xrv[j] + ac[i][j]);
            sredH[(gm & 31) * 66 + tn * 4 + j] = tvv[j];
            sredG[(gm & 31) * 66 + tn * 4 + j] = r * tvv[j];
        }
    }
    __syncthreads();
    {
        const int bl = tid >> 6, col = tid & 63;   // 4 local b's x 64 cols = 256
        const int b = rt * 4 + bl;
        float sh = 0.f, sg = 0.f;
#pragma unroll
        for (int n = 0; n < 8; ++n) {
            sh += sredH[(bl * 8 + n) * 66 + col];
            sg += sredG[(bl * 8 + n) * 66 + col];
        }
        sumh[(size_t)b * H + col0 + col] = sh;
        sumg[(size_t)b * H + col0 + col] = sg;
    }
    __syncthreads();   // sred/As reuse by next job
}

// ===========================================================================
// Persistent loop: 2 device-wide syncs per step
//   A: zh(t) [blocks 0-127] || xgather(t+1) [blocks 128-255]
//   C: fused hU+sums(t+1)   [all 256 blocks x 4 tile-jobs]
// ===========================================================================
__global__ __launch_bounds__(256)
void loop_k2(const int* __restrict__ nei_h, const float* __restrict__ node_rep,
             const int* __restrict__ cliq,
             const float* __restrict__ Wz, const float* __restrict__ bz,
             const float* __restrict__ Wh, const float* __restrict__ bh,
             const float* __restrict__ Ur, const float* __restrict__ xr_all,
             float* table, float* xb0, float* xb1, float* sumh, float* sumg,
             unsigned* bar)
{
    __shared__ float smem[7616];
    const int bid = blockIdx.x, tid = threadIdx.x;
    unsigned epoch = 0;

    for (int t = 0; t < T; ++t) {
        float* xbc = (t & 1) ? xb1 : xb0;
        float* xbn = (t & 1) ? xb0 : xb1;
        if (bid < 128) {
            ph_zh(t, bid, tid, smem, smem + 1216, smem + 2432, smem + 4608,
                  xbc, sumh, sumg, Wz, bz, Wh, bh, table);
        } else if (t + 1 < T) {
            const int base = (bid - 128) * 512 + tid;
            ph_xgather(t + 1, base,       node_rep, cliq, xbn);
            ph_xgather(t + 1, base + 256, node_rep, cliq, xbn);
        }
        if (t + 1 == T) break;
        gbar2(bar, epoch, bid);
#pragma unroll 1
        for (int q = 0; q < 4; ++q)
            ph_sums2(t + 1, bid + q * 256, tid, smem, smem + 1216,
                     smem + 3392, smem + 5504,
                     nei_h, xr_all, table, Ur, sumh, sumg);
        gbar2(bar, epoch, bid);
    }
}

// pre-loop x gather for t=0
__global__ __launch_bounds__(256)
void xg0_k(const float* __restrict__ node_rep, const int* __restrict__ cliq,
           float* __restrict__ xb)
{
    ph_xgather(0, blockIdx.x * 256 + threadIdx.x, node_rep, cliq, xb);
}

// ===========================================================================
// Post-loop: o_all from FINAL table with step mask ((idx-1)&63 < t)  (verified)
// ===========================================================================
__global__ __launch_bounds__(256)
void oall_k(const int* __restrict__ nei_o, const float* __restrict__ table,
            float* __restrict__ o_all)
{
    const int i = blockIdx.x * 256 + threadIdx.x;   // BT*H/4
    const int m = i >> 7, h4 = (i & 127) * 4;
    const int t = m & 63;
    const int* oi = nei_o + (size_t)m * NB;
    float4 s = {0.f, 0.f, 0.f, 0.f};
#pragma unroll
    for (int n = 0; n < NB; ++n) {
        const int idx = oi[n];
        if (idx != 0 && ((idx - 1) & 63) < t) {
            const float4 hv = *(const float4*)&table[(size_t)idx * H + h4];
            s.x += hv.x; s.y += hv.y; s.z += hv.z; s.w += hv.w;
        }
    }
    *(float4*)&o_all[(size_t)m * H + h4] = s;
}

// ===========================================================================
// Heads (verified r8/r10): 64x64-tile GEMM
// ASRC: 0 plain | 3 stop (seg0 clique gather / root, seg1 A2 / root-nei)
// EPI: 0 none | 3 relu | 4 relu*Usw partial
// ===========================================================================
constexpr size_t SM_GEMM = (size_t)(2 * 32 * 68) * 4;
constexpr size_t SM_STOP = (size_t)(2 * 32 * 68 + 64 * 17) * 4;

template<int ASRC, int NSEG, int EPI>
__global__ __launch_bounds__(256)
void gemm_g(const float* __restrict__ A1, const float* __restrict__ A2, int lda,
            const float* __restrict__ W, const float* __restrict__ bias,
            float* __restrict__ C, int ldc,
            const float* __restrict__ node_rep, const int* __restrict__ cliq,
            const int* __restrict__ rci, const int* __restrict__ rni,
            const float* __restrict__ table,
            const float* __restrict__ Usw, float* __restrict__ partial)
{
    extern __shared__ float smem[];
    float* As = smem;
    float* Ws = smem + 32 * 68;
    const int tid = threadIdx.x, row0 = blockIdx.x * 64, col0 = blockIdx.y * 64;
    const int tm = tid >> 4, tn = tid & 15;
    const int ar0 = tid >> 5, ac = tid & 31, wk0 = tid >> 6, wc = tid & 63;
    float acc[4][4] = {};

    for (int seg = 0; seg < NSEG; ++seg) {
        const float* Wseg = W + (size_t)seg * H * H;
        for (int k0 = 0; k0 < H; k0 += 32) {
#pragma unroll
            for (int it = 0; it < 8; ++it) {
                const int r = ar0 + it * 8, grow = row0 + r;
                float v;
                if (ASRC == 0) {
                    v = A1[(size_t)grow * lda + k0 + ac];
                } else {
                    if (grow < BT) {
                        if (seg == 0) {
                            const int* ci = cliq + (size_t)grow * KC;
                            const int b = grow >> 6;
                            v = 0.f;
#pragma unroll
                            for (int j = 0; j < KC; ++j)
                                v += node_rep[((size_t)b * N_AT + ci[j]) * H + k0 + ac];
                        } else {
                            v = A2[(size_t)grow * H + k0 + ac];
                        }
                    } else {
                        const int b = grow - BT;
                        v = 0.f;
                        if (seg == 0) {
#pragma unroll
                            for (int j = 0; j < KC; ++j)
                                v += node_rep[((size_t)b * N_AT + rci[b * KC + j]) * H + k0 + ac];
                        } else {
#pragma unroll
                            for (int n = 0; n < NB; ++n)
                                v += table[(size_t)rni[b * NB + n] * H + k0 + ac];
                        }
                    }
                }
                As[(size_t)ac * 68 + r] = v;
                const int kk = wk0 + it * 4;
                Ws[(size_t)kk * 68 + wc] = Wseg[(size_t)(k0 + kk) * H + col0 + wc];
            }
            __syncthreads();
#pragma unroll
            for (int kk = 0; kk < 32; ++kk) {
                float a[4], w[4];
                *(float4*)a = *(const float4*)&As[kk * 68 + tm * 4];
                *(float4*)w = *(const float4*)&Ws[kk * 68 + tn * 4];
#pragma unroll
                for (int i = 0; i < 4; ++i)
#pragma unroll
                    for (int j = 0; j < 4; ++j)
                        acc[i][j] = fmaf(a[i], w[j], acc[i][j]);
            }
            __syncthreads();
        }
    }

    if (EPI == 4) {
        float* sred = smem + 2 * 32 * 68;   // [64][17]
#pragma unroll
        for (int i = 0; i < 4; ++i) {
            float s = 0.f;
#pragma unroll
            for (int j = 0; j < 4; ++j) {
                const int c = col0 + tn * 4 + j;
                s += fmaxf(acc[i][j] + bias[c], 0.f) * Usw[c];
            }
            sred[(size_t)(tm * 4 + i) * 17 + tn] = s;
        }
        __syncthreads();
        if (tid < 64) {
            float s = 0.f;
#pragma unroll
            for (int q = 0; q < 16; ++q) s += sred[(size_t)tid * 17 + q];
            partial[(size_t)(row0 + tid) * 8 + blockIdx.y] = s;
        }
    } else {
#pragma unroll
        for (int i = 0; i < 4; ++i) {
            const int r = row0 + tm * 4 + i;
            float out[4];
#pragma unroll
            for (int j = 0; j < 4; ++j) {
                float val = acc[i][j] + (bias ? bias[col0 + tn * 4 + j] : 0.f);
                if (EPI == 3) val = fmaxf(val, 0.f);
                out[j] = val;
            }
            *(float4*)&C[(size_t)r * ldc + col0 + tn * 4] = *(float4*)out;
        }
    }
}

__global__ __launch_bounds__(256)
void stopfin_kernel(const float* __restrict__ partial, const float* __restrict__ Usb,
                    const int* __restrict__ direction, float* __restrict__ accum)
{
    const int i = blockIdx.x * 256 + threadIdx.x;   // BT+B exactly
    float loss = 0.f, acc = 0.f;
    {
        float s = Usb[0];
#pragma unroll
        for (int cb = 0; cb < 8; ++cb) s += partial[(size_t)i * 8 + cb];
        const float tgt = (i < BT) ? (float)direction[i] : 0.f;
        loss = fmaxf(s, 0.f) - s * tgt + log1pf(expf(-fabsf(s)));
        const float p = (s >= 0.f) ? 1.f : 0.f;
        acc = (p == tgt) ? 1.f : 0.f;
    }
#pragma unroll
    for (int off = 32; off; off >>= 1) {
        loss += __shfl_down(loss, off);
        acc  += __shfl_down(acc, off);
    }
    if ((threadIdx.x & 63) == 0) {
        atomicAdd(&accum[3], loss);
        atomicAdd(&accum[4], acc);
    }
}

// pred head phase 2 (verified): fused scores GEMM + log-softmax CE + argmax
__global__ __launch_bounds__(256)
void ce_kernel(const float* __restrict__ s1_all, const float* __restrict__ Wo,
               const float* __restrict__ Wob, const int* __restrict__ direction,
               const int* __restrict__ ptgt, float* __restrict__ accum)
{
    __shared__ float s1T[512 * 34];
    __shared__ float Ws[32 * 68];
    __shared__ float blk[3];
    const int tid  = threadIdx.x;
    const int row0 = blockIdx.x * 32;

    for (int idx = tid; idx < 32 * 512; idx += 256) {
        const int r = idx >> 9, k = idx & 511;
        s1T[(size_t)k * 34 + r] = s1_all[(size_t)(row0 + r) * H + k];
    }
    if (tid < 3) blk[tid] = 0.f;
    __syncthreads();

    const int tm = tid >> 4, tn = tid & 15;
    const int tgt0 = ptgt[row0 + tm * 2];
    const int tgt1 = ptgt[row0 + tm * 2 + 1];
    float m0 = -1e30f, m1 = -1e30f, ss0 = 0.f, ss1 = 0.f, st0 = 0.f, st1 = 0.f;
    float bv0 = -1e30f, bv1 = -1e30f;
    int   bj0 = 0, bj1 = 0;

    for (int ct = 0; ct < 13; ++ct) {
        const int col0 = ct * 64;
        float acc[2][4] = {};
        for (int k0 = 0; k0 < 512; k0 += 32) {
#pragma unroll
            for (int it = 0; it < 8; ++it) {
                const int idx = tid + it * 256;
                const int kk = idx >> 6, cc = idx & 63;
                const int col = col0 + cc;
                Ws[(size_t)kk * 68 + cc] = (col < V) ? Wo[(size_t)(k0 + kk) * V + col] : 0.f;
            }
            __syncthreads();
#pragma unroll
            for (int kk = 0; kk < 32; ++kk) {
                const float a0 = s1T[(size_t)(k0 + kk) * 34 + tm * 2];
                const float a1 = s1T[(size_t)(k0 + kk) * 34 + tm * 2 + 1];
                float w[4];
                *(float4*)w = *(const float4*)&Ws[kk * 68 + tn * 4];
#pragma unroll
                for (int j = 0; j < 4; ++j) {
                    acc[0][j] = fmaf(a0, w[j], acc[0][j]);
                    acc[1][j] = fmaf(a1, w[j], acc[1][j]);
                }
            }
            __syncthreads();
        }
#pragma unroll
        for (int j = 0; j < 4; ++j) {
            const int col = col0 + tn * 4 + j;
            if (col < V) {
                const float wb  = Wob[col];
                const float sc0 = acc[0][j] + wb;
                const float sc1 = acc[1][j] + wb;
                if (sc0 > m0) { ss0 = ss0 * expf(m0 - sc0) + 1.f; m0 = sc0; }
                else          { ss0 += expf(sc0 - m0); }
                if (sc1 > m1) { ss1 = ss1 * expf(m1 - sc1) + 1.f; m1 = sc1; }
                else          { ss1 += expf(sc1 - m1); }
                if (sc0 > bv0) { bv0 = sc0; bj0 = col; }
                if (sc1 > bv1) { bv1 = sc1; bj1 = col; }
                if (col == tgt0) st0 = sc0;
                if (col == tgt1) st1 = sc1;
            }
        }
    }

#pragma unroll
    for (int off = 1; off < 16; off <<= 1) {
        float om, os;
        om = __shfl_xor(m0, off); os = __shfl_xor(ss0, off);
        { const float nm = fmaxf(m0, om); ss0 = ss0 * expf(m0 - nm) + os * expf(om - nm); m0 = nm; }
        om = __shfl_xor(m1, off); os = __shfl_xor(ss1, off);
        { const float nm = fmaxf(m1, om); ss1 = ss1 * expf(m1 - nm) + os * expf(om - nm); m1 = nm; }
        float obv; int obj;
        obv = __shfl_xor(bv0, off); obj = __shfl_xor(bj0, off);
        if (obv > bv0 || (obv == bv0 && obj < bj0)) { bv0 = obv; bj0 = obj; }
        obv = __shfl_xor(bv1, off); obj = __shfl_xor(bj1, off);
        if (obv > bv1 || (obv == bv1 && obj < bj1)) { bv1 = obv; bj1 = obj; }
        st0 += __shfl_xor(st0, off);
        st1 += __shfl_xor(st1, off);
    }
    if (tn == 0) {
        float ce_s = 0.f, cnt = 0.f, corr = 0.f;
        {
            const int row = row0 + tm * 2;
            if (direction[row] == 1) {
                ce_s += (m0 + logf(ss0)) - st0; cnt += 1.f;
                corr += (bj0 == tgt0) ? 1.f : 0.f;
            }
        }
        {
            const int row = row0 + tm * 2 + 1;
            if (direction[row] == 1) {
                ce_s += (m1 + logf(ss1)) - st1; cnt += 1.f;
                corr += (bj1 == tgt1) ? 1.f : 0.f;
            }
        }
        atomicAdd(&blk[0], ce_s); atomicAdd(&blk[1], cnt); atomicAdd(&blk[2], corr);
    }
    __syncthreads();
    if (tid == 0) {
        atomicAdd(&accum[0], blk[0]);
        atomicAdd(&accum[1], blk[1]);
        atomicAdd(&accum[2], blk[2]);
    }
}

__global__ void finalize_kernel(const float* __restrict__ accum, float* __restrict__ out)
{
    if (threadIdx.x == 0) {
        out[0] = accum[0] / (float)B;
        out[1] = accum[3] / (float)B;
        out[2] = accum[2] / accum[1];
        out[3] = accum[4] / (float)(BT + B);
    }
}

// ===========================================================================
extern "C" void kernel_launch(void* const* d_in, const int* in_sizes, int n_in,
                              void* d_out, int out_size, void* d_ws, size_t ws_size,
                              hipStream_t stream)
{
    (void)in_sizes; (void)n_in; (void)out_size; (void)ws_size;

    const float* node_rep        = (const float*)d_in[0];
    const int*   clique_idx      = (const int*)d_in[1];
    const int*   root_clique_idx = (const int*)d_in[2];
    const int*   nei_h_idx       = (const int*)d_in[3];
    const int*   nei_o_idx       = (const int*)d_in[4];
    const int*   root_nei_idx    = (const int*)d_in[5];
    const int*   direction       = (const int*)d_in[6];
    const int*   pred_target     = (const int*)d_in[7];
    const float* W_z_w = (const float*)d_in[8];
    const float* W_z_b = (const float*)d_in[9];
    const float* W_r_w = (const float*)d_in[10];
    const float* W_r_b = (const float*)d_in[11];
    const float* U_r_w = (const float*)d_in[12];
    const float* W_h_w = (const float*)d_in[13];
    const float* W_h_b = (const float*)d_in[14];
    const float* W_w   = (const float*)d_in[15];
    const float* W_b   = (const float*)d_in[16];
    const float* U_w   = (const float*)d_in[17];
    const float* U_b   = (const float*)d_in[18];
    const float* W_o_w = (const float*)d_in[19];
    const float* W_o_b = (const float*)d_in[20];
    const float* U_s_w = (const float*)d_in[21];
    const float* U_s_b = (const float*)d_in[22];

    // ---- memory plan: 141.5 MB (proven ws >= 152.3 MB from round-5 profile) ----
    float* ws = (float*)d_ws;
    size_t off = 0;
    auto alloc = [&](size_t n) { float* p = ws + off; off += n; return p; };

    float* table   = alloc((size_t)NMSG * H);   // 67.1 MB
    float* xr_all  = alloc((size_t)BT * H);     // 67.1 MB; o_all/s1 region after loop
    float* xb0     = alloc(BH);
    float* xb1     = alloc(BH);
    float* sumh    = alloc(BH);
    float* sumg    = alloc(BH);
    float* partial = alloc((size_t)(BT + B) * 8);
    float* accum   = alloc(8);
    float* barf    = alloc(160);                // hierarchical barrier counters
    unsigned* bar  = (unsigned*)barf;

    hipMemsetAsync(table, 0, (size_t)NMSG * H * sizeof(float), stream);
    hipMemsetAsync(sumh, 0, (size_t)BH * sizeof(float), stream);
    hipMemsetAsync(sumg, 0, (size_t)BH * sizeof(float), stream);
    hipMemsetAsync(accum, 0, 8 * sizeof(float), stream);
    hipMemsetAsync(barf, 0, 160 * sizeof(float), stream);

    // pre-loop: x for t=0; xr_all = cliquegather(node_rep) @ W_r + b_r (all BT rows)
    xg0_k<<<256, 256, 0, stream>>>(node_rep, clique_idx, xb0);
    gemm_g<3, 1, 0><<<dim3(BT / 64, 8), 256, SM_GEMM, stream>>>(
        nullptr, nullptr, 0, W_r_w, W_r_b, xr_all, H,
        node_rep, clique_idx, root_clique_idx, root_nei_idx,
        nullptr, nullptr, nullptr);

    // ---- persistent loop: 2 hierarchical-barrier syncs per step ----
    loop_k2<<<NBLK, 256, 0, stream>>>(
        nei_h_idx, node_rep, clique_idx, W_z_w, W_z_b, W_h_w, W_h_b,
        U_r_w, xr_all, table, xb0, xb1, sumh, sumg, bar);

    // ---- heads (xr_all region reused: o_all, then s1) ----
    float* region = xr_all;
    oall_k<<<BT * H / 4 / 256, 256, 0, stream>>>(nei_o_idx, table, region);
    gemm_g<3, 2, 4><<<dim3((BT + B) / 64, 8), 256, SM_STOP, stream>>>(
        nullptr, region, 0, U_w, U_b, nullptr, 0,
        node_rep, clique_idx, root_clique_idx, root_nei_idx,
        table, U_s_w, partial);
    stopfin_kernel<<<(BT + B) / 256, 256, 0, stream>>>(partial, U_s_b, direction, accum);

    gemm_g<0, 1, 3><<<dim3(BT / 64, 8), 256, SM_GEMM, stream>>>(
        table + H, nullptr, H, W_w, W_b, region, H,
        nullptr, nullptr, nullptr, nullptr, nullptr, nullptr, nullptr);
    ce_kernel<<<BT / 32, 256, 0, stream>>>(region, W_o_w, W_o_b,
                                           direction, pred_target, accum);

    finalize_kernel<<<1, 64, 0, stream>>>(accum, (float*)d_out);
}